// Round 2
// baseline (390.931 us; speedup 1.0000x reference)
//
#include <hip/hip_runtime.h>

#define Bn   8
#define Cn   64
#define Hn   128
#define Wn   128
#define KK   9
#define OffC 18
#define NG   4
#define Cg   16
#define HW   (Hn*Wn)

#define OFFS_ELEMS (Bn*OffC*HW)    // 2359296 floats
#define WT2_ELEMS  (Cn*KK*OffC)    // 10368
#define WT_ELEMS   (NG*KK*Cg*Cg)   // 2304

// ---------------- Kernel 0: transpose weights into contraction-friendly layouts --------
// wt2[ci][k][o]  (o contiguous, 18)   from offw[o][ci][ky][kx]
// wt [g][k][c][o] (o contiguous, 16)  from dw[g*16+o][c][ky][kx]
__global__ __launch_bounds__(256) void transpose_w_kernel(
    const float* __restrict__ offw, const float* __restrict__ dw,
    float* __restrict__ wt2, float* __restrict__ wt)
{
    const int tid = blockIdx.x * 256 + threadIdx.x;
    const int nth = gridDim.x * 256;
    for (int i = tid; i < WT2_ELEMS; i += nth) {
        const int o  = i % OffC;
        const int k  = (i / OffC) % KK;
        const int ci = i / (OffC * KK);
        wt2[i] = offw[(o * Cn + ci) * KK + k];
    }
    for (int i = tid; i < WT_ELEMS; i += nth) {
        const int o = i % Cg;
        const int c = (i / Cg) % Cg;
        const int k = (i / (Cg * Cg)) % KK;
        const int g = i / (Cg * Cg * KK);
        wt[i] = dw[((g * Cg + o) * Cg + c) * KK + k];
    }
}

// ---------------- Kernel 1: offset conv (3x3, 64 -> 18, pad 1) ----------------
// 256 threads: 4 rows x (2 pixels/thread). Weights via uniform s_load (SGPR broadcast).
__global__ __launch_bounds__(256) void offset_conv_kernel(
    const float* __restrict__ x, const float* __restrict__ wt2,
    const float* __restrict__ bias, float* __restrict__ offs)
{
    const int tid = threadIdx.x;
    const int rb  = blockIdx.x % (Hn / 4);
    const int b   = blockIdx.x / (Hn / 4);
    const int row = tid >> 6;       // 0..3
    const int wo0 = tid & 63;       // pixel pair (wo0, wo0+64)
    const int ho  = rb * 4 + row;

    float acc0[OffC], acc1[OffC];
#pragma unroll
    for (int o = 0; o < OffC; o++) { const float bv = bias[o]; acc0[o] = bv; acc1[o] = bv; }

    const float* xb = x + (size_t)b * Cn * HW;
    for (int ci = 0; ci < Cn; ci++) {
        const float* xc   = xb + ci * HW;
        const float* wrow = wt2 + ci * (KK * OffC);
#pragma unroll
        for (int ky = 0; ky < 3; ky++) {
            const int  y   = ho - 1 + ky;
            const bool yok = ((unsigned)y < (unsigned)Hn);
            const float* xr = xc + y * Wn;
#pragma unroll
            for (int kx = 0; kx < 3; kx++) {
                const int xa  = wo0 - 1 + kx;
                const int xb2 = wo0 + 63 + kx;
                const float v0 = (yok && (unsigned)xa  < (unsigned)Wn) ? xr[xa]  : 0.f;
                const float v1 = (yok && (unsigned)xb2 < (unsigned)Wn) ? xr[xb2] : 0.f;
                const float* wk = wrow + (ky * 3 + kx) * OffC;   // uniform address
#pragma unroll
                for (int o = 0; o < OffC; o++) {
                    const float wv = wk[o];        // -> s_load, SGPR operand
                    acc0[o] += v0 * wv;
                    acc1[o] += v1 * wv;
                }
            }
        }
    }

    float* ob = offs + ((size_t)b * OffC * Hn + ho) * Wn;
#pragma unroll
    for (int o = 0; o < OffC; o++) {
        ob[o * HW + wo0]      = acc0[o];
        ob[o * HW + wo0 + 64] = acc1[o];
    }
}

// ---------------- Kernel 2: grouped deformable conv ----------------
// 256 threads: 2 rows x 128 cols, 1 pixel/thread, 16 output channels in regs.
// No LDS. Weights via uniform s_load. 64 independent gather loads per tap.
__global__ __launch_bounds__(256) void deform_kernel(
    const float* __restrict__ skip, const float* __restrict__ offs,
    const float* __restrict__ wt, float* __restrict__ out)
{
    const int tid = threadIdx.x;
    const int g   = blockIdx.y & 3;
    const int b   = blockIdx.y >> 2;
    const int row = tid >> 7;        // 0..1
    const int wo  = tid & 127;
    const int ho  = blockIdx.x * 2 + row;

    float acc[Cg];
#pragma unroll
    for (int o = 0; o < Cg; o++) acc[o] = 0.f;

    const float* sg   = skip + (size_t)(b * Cn + g * Cg) * HW;
    const float* offp = offs + (size_t)b * OffC * HW + ho * Wn + wo;
    const float* wg   = wt + g * (KK * Cg * Cg);

    for (int k = 0; k < KK; k++) {     // not unrolled: keeps code size I$-friendly
        const int ky = k / 3, kx = k % 3;
        const float offy = offp[(2 * k)     * HW];
        const float offx = offp[(2 * k + 1) * HW];
        const float py = (float)(ho - 1 + ky) + offy;
        const float px = (float)(wo - 1 + kx) + offx;
        const float y0f = floorf(py), x0f = floorf(px);
        const float wy = py - y0f, wx = px - x0f;
        const int y0 = (int)y0f, x0 = (int)x0f;
        const int y1 = y0 + 1,  x1 = x0 + 1;
        const bool vy0 = ((unsigned)y0 < (unsigned)Hn);
        const bool vy1 = ((unsigned)y1 < (unsigned)Hn);
        const bool vx0 = ((unsigned)x0 < (unsigned)Wn);
        const bool vx1 = ((unsigned)x1 < (unsigned)Wn);
        const int y0c = min(max(y0, 0), Hn - 1), y1c = min(max(y1, 0), Hn - 1);
        const int x0c = min(max(x0, 0), Wn - 1), x1c = min(max(x1, 0), Wn - 1);
        const float m00 = (1.f - wy) * (1.f - wx) * ((vy0 && vx0) ? 1.f : 0.f);
        const float m01 = (1.f - wy) * wx         * ((vy0 && vx1) ? 1.f : 0.f);
        const float m10 = wy * (1.f - wx)         * ((vy1 && vx0) ? 1.f : 0.f);
        const float m11 = wy * wx                 * ((vy1 && vx1) ? 1.f : 0.f);
        const int i00 = y0c * Wn + x0c;
        const int i01 = y0c * Wn + x1c;
        const int i10 = y1c * Wn + x0c;
        const int i11 = y1c * Wn + x1c;
        const float* wk = wg + k * (Cg * Cg);    // uniform address

#pragma unroll
        for (int c = 0; c < Cg; c++) {
            const float* sc = sg + c * HW;
            const float v00 = sc[i00], v01 = sc[i01], v10 = sc[i10], v11 = sc[i11];
            const float s = v00 * m00 + v01 * m01 + v10 * m10 + v11 * m11;
            const float* wc = wk + c * Cg;       // uniform
#pragma unroll
            for (int o = 0; o < Cg; o++) acc[o] += s * wc[o];   // v_fmac v,s,v
        }
    }

    float* ob = out + ((size_t)(b * Cn + g * Cg) * Hn + ho) * Wn + wo;
#pragma unroll
    for (int o = 0; o < Cg; o++) ob[o * HW] = acc[o];
}

extern "C" void kernel_launch(void* const* d_in, const int* in_sizes, int n_in,
                              void* d_out, int out_size, void* d_ws, size_t ws_size,
                              hipStream_t stream) {
    const float* x        = (const float*)d_in[0];
    const float* skip     = (const float*)d_in[1];
    const float* offset_w = (const float*)d_in[2];
    const float* offset_b = (const float*)d_in[3];
    const float* deform_w = (const float*)d_in[4];
    float* out  = (float*)d_out;

    float* offs = (float*)d_ws;                // 9.44 MB
    float* wt2  = offs + OFFS_ELEMS;           // 41.5 KB
    float* wt   = wt2 + WT2_ELEMS;             // 9.2 KB

    hipLaunchKernelGGL(transpose_w_kernel, dim3(8), dim3(256), 0, stream,
                       offset_w, deform_w, wt2, wt);
    hipLaunchKernelGGL(offset_conv_kernel, dim3(Bn * Hn / 4), dim3(256), 0, stream,
                       x, wt2, offset_b, offs);
    hipLaunchKernelGGL(deform_kernel, dim3(Hn / 2, Bn * NG), dim3(256), 0, stream,
                       skip, offs, wt, out);
}

// Round 3
// 221.690 us; speedup vs baseline: 1.7634x; 1.7634x over previous
//
#include <hip/hip_runtime.h>

#define Bn    8
#define Cn    64
#define Hn    128
#define Wn    128
#define KK    9
#define OffC  18
#define OffCp 20        // padded to float4 granularity
#define NG    4
#define Cg    16
#define HW    (Hn*Wn)
#define CSPLIT 4
#define CCH   (Cn/CSPLIT)   // 16 input channels per block

#define OFFS_ELEMS (Bn*OffC*HW)     // 2359296 floats
#define WT2_ELEMS  (Cn*KK*OffCp)    // 11520
#define WT_ELEMS   (NG*KK*Cg*Cg)    // 2304

// ---------- Kernel 0a: transpose weights into contraction-friendly layouts ----------
// wt2[ci][k][o] (o contiguous, padded to 20)  from offw[o][ci][ky][kx]
// wt [g][k][c][o] (o contiguous, 16)          from dw[g*16+o][c][ky][kx]
__global__ __launch_bounds__(256) void transpose_w_kernel(
    const float* __restrict__ offw, const float* __restrict__ dw,
    float* __restrict__ wt2, float* __restrict__ wt)
{
    const int tid = blockIdx.x * 256 + threadIdx.x;
    const int nth = gridDim.x * 256;
    for (int i = tid; i < WT2_ELEMS; i += nth) {
        const int o  = i % OffCp;
        const int k  = (i / OffCp) % KK;
        const int ci = i / (OffCp * KK);
        wt2[i] = (o < OffC) ? offw[(o * Cn + ci) * KK + k] : 0.f;
    }
    for (int i = tid; i < WT_ELEMS; i += nth) {
        const int o = i % Cg;
        const int c = (i / Cg) % Cg;
        const int k = (i / (Cg * Cg)) % KK;
        const int g = i / (Cg * Cg * KK);
        wt[i] = dw[((g * Cg + o) * Cg + c) * KK + k];
    }
}

// ---------- Kernel 0b: init offs with bias (atomic partials add onto this) ----------
__global__ __launch_bounds__(256) void init_offs_kernel(
    const float* __restrict__ bias, float* __restrict__ offs)
{
    const int i4 = blockIdx.x * 256 + threadIdx.x;        // float4 index
    if (i4 * 4 >= OFFS_ELEMS) return;
    const int o = ((i4 * 4) / HW) % OffC;
    const float bv = bias[o];
    ((float4*)offs)[i4] = make_float4(bv, bv, bv, bv);
}

// ---------- Kernel 1: offset conv (3x3, 64->18, pad 1), ci-split x4, atomic finish ----
// grid (Hn/4, Bn, CSPLIT), 256 threads. Thread: 1 col x 2 rows, 18 outs, 16 ci.
__global__ __launch_bounds__(256, 4) void offset_conv_kernel(
    const float* __restrict__ x, const float* __restrict__ wt2,
    float* __restrict__ offs)
{
    __shared__ float wl[CCH * KK * OffCp];   // 2880 floats = 11.5 KB
    const int tid = threadIdx.x;
    const int ci0 = blockIdx.z * CCH;
    {
        const float* src = wt2 + ci0 * (KK * OffCp);
        for (int i = tid; i < CCH * KK * OffCp; i += 256) wl[i] = src[i];
    }
    __syncthreads();

    const int b   = blockIdx.y;
    const int col = tid & 127;
    const int rp  = tid >> 7;                 // 0..1
    const int r0  = blockIdx.x * 4 + rp * 2;  // rows r0, r0+1

    float acc[2][OffC];
#pragma unroll
    for (int p = 0; p < 2; p++)
#pragma unroll
        for (int o = 0; o < OffC; o++) acc[p][o] = 0.f;

    const float* xb = x + ((size_t)b * Cn + ci0) * HW;
    for (int i = 0; i < CCH; ++i) {
        const float* xc = xb + i * HW;
        // hoisted input loads: 4 rows x 3 col-window, reused by both pixels' 9 taps
        float rowv[4][3];
#pragma unroll
        for (int rr = 0; rr < 4; ++rr) {
            const int  y   = r0 - 1 + rr;
            const bool yok = ((unsigned)y < (unsigned)Hn);
#pragma unroll
            for (int kx = 0; kx < 3; ++kx) {
                const int xcol = col - 1 + kx;
                rowv[rr][kx] = (yok && (unsigned)xcol < (unsigned)Wn)
                               ? xc[y * Wn + xcol] : 0.f;
            }
        }
        const float* wci = wl + i * (KK * OffCp);
#pragma unroll
        for (int ky = 0; ky < 3; ++ky) {
#pragma unroll
            for (int kx = 0; kx < 3; ++kx) {
                const float4* wk4 = (const float4*)(wci + (ky * 3 + kx) * OffCp);
                const float4 w0 = wk4[0], w1 = wk4[1], w2 = wk4[2], w3 = wk4[3];
                const float2 w4 = *(const float2*)(wk4 + 4);
                const float w[OffC] = { w0.x,w0.y,w0.z,w0.w, w1.x,w1.y,w1.z,w1.w,
                                        w2.x,w2.y,w2.z,w2.w, w3.x,w3.y,w3.z,w3.w,
                                        w4.x,w4.y };
#pragma unroll
                for (int p = 0; p < 2; p++) {
                    const float v = rowv[p + ky][kx];
#pragma unroll
                    for (int o = 0; o < OffC; o++) acc[p][o] += v * w[o];
                }
            }
        }
    }

#pragma unroll
    for (int p = 0; p < 2; p++) {
        float* ob = offs + (((size_t)b * OffC) * Hn + (r0 + p)) * Wn + col;
#pragma unroll
        for (int o = 0; o < OffC; o++) atomicAdd(ob + o * HW, acc[p][o]);
    }
}

// ---------- Kernel 2: grouped deformable conv, 2 px/thread ----------
// grid (Hn/4, Bn*NG), 256 threads. Thread: 1 col x 2 rows, 16 out channels.
__global__ __launch_bounds__(256, 4) void deform_kernel(
    const float* __restrict__ skip, const float* __restrict__ offs,
    const float* __restrict__ wt, float* __restrict__ out)
{
    __shared__ float wl[KK * Cg * Cg];   // 2304 floats = 9.2 KB
    const int tid = threadIdx.x;
    const int g = blockIdx.y & 3;
    const int b = blockIdx.y >> 2;
    for (int i = tid; i < KK * Cg * Cg; i += 256) wl[i] = wt[g * (KK * Cg * Cg) + i];
    __syncthreads();

    const int col = tid & 127;
    const int rp  = tid >> 7;
    const int r0  = blockIdx.x * 4 + rp * 2;   // rows r0, r0+1

    float acc[2][Cg];
#pragma unroll
    for (int p = 0; p < 2; p++)
#pragma unroll
        for (int o = 0; o < Cg; o++) acc[p][o] = 0.f;

    const float* sg   = skip + (size_t)(b * Cn + g * Cg) * HW;
    const float* offb = offs + (size_t)b * OffC * HW;

    for (int k = 0; k < KK; k++) {
        const int ky = k / 3, kx = k % 3;
        int   idx[2][4];
        float m[2][4];
#pragma unroll
        for (int p = 0; p < 2; p++) {
            const int row = r0 + p;
            const float offy = offb[(2 * k)     * HW + row * Wn + col];
            const float offx = offb[(2 * k + 1) * HW + row * Wn + col];
            const float py = (float)(row - 1 + ky) + offy;
            const float px = (float)(col - 1 + kx) + offx;
            const float y0f = floorf(py), x0f = floorf(px);
            const float wy = py - y0f, wx = px - x0f;
            const int y0 = (int)y0f, x0 = (int)x0f;
            const int y1 = y0 + 1,  x1 = x0 + 1;
            const bool vy0 = ((unsigned)y0 < (unsigned)Hn);
            const bool vy1 = ((unsigned)y1 < (unsigned)Hn);
            const bool vx0 = ((unsigned)x0 < (unsigned)Wn);
            const bool vx1 = ((unsigned)x1 < (unsigned)Wn);
            const int y0c = min(max(y0, 0), Hn - 1), y1c = min(max(y1, 0), Hn - 1);
            const int x0c = min(max(x0, 0), Wn - 1), x1c = min(max(x1, 0), Wn - 1);
            m[p][0] = (1.f - wy) * (1.f - wx) * ((vy0 && vx0) ? 1.f : 0.f);
            m[p][1] = (1.f - wy) * wx         * ((vy0 && vx1) ? 1.f : 0.f);
            m[p][2] = wy * (1.f - wx)         * ((vy1 && vx0) ? 1.f : 0.f);
            m[p][3] = wy * wx                 * ((vy1 && vx1) ? 1.f : 0.f);
            idx[p][0] = y0c * Wn + x0c;
            idx[p][1] = y0c * Wn + x1c;
            idx[p][2] = y1c * Wn + x0c;
            idx[p][3] = y1c * Wn + x1c;
        }

#pragma unroll
        for (int c = 0; c < Cg; c++) {
            const float* sc = sg + c * HW;
            const float a00 = sc[idx[0][0]], a01 = sc[idx[0][1]],
                        a10 = sc[idx[0][2]], a11 = sc[idx[0][3]];
            const float b00 = sc[idx[1][0]], b01 = sc[idx[1][1]],
                        b10 = sc[idx[1][2]], b11 = sc[idx[1][3]];
            const float s0 = a00 * m[0][0] + a01 * m[0][1] + a10 * m[0][2] + a11 * m[0][3];
            const float s1 = b00 * m[1][0] + b01 * m[1][1] + b10 * m[1][2] + b11 * m[1][3];
            const float4* wc4 = (const float4*)(wl + (k * Cg + c) * Cg);
            const float4 w0 = wc4[0], w1 = wc4[1], w2 = wc4[2], w3 = wc4[3];
            const float w[Cg] = { w0.x,w0.y,w0.z,w0.w, w1.x,w1.y,w1.z,w1.w,
                                  w2.x,w2.y,w2.z,w2.w, w3.x,w3.y,w3.z,w3.w };
#pragma unroll
            for (int o = 0; o < Cg; o++) {
                acc[0][o] += s0 * w[o];
                acc[1][o] += s1 * w[o];
            }
        }
    }

#pragma unroll
    for (int p = 0; p < 2; p++) {
        float* ob = out + (((size_t)(b * Cn + g * Cg)) * Hn + (r0 + p)) * Wn + col;
#pragma unroll
        for (int o = 0; o < Cg; o++) ob[o * HW] = acc[p][o];
    }
}

extern "C" void kernel_launch(void* const* d_in, const int* in_sizes, int n_in,
                              void* d_out, int out_size, void* d_ws, size_t ws_size,
                              hipStream_t stream) {
    const float* x        = (const float*)d_in[0];
    const float* skip     = (const float*)d_in[1];
    const float* offset_w = (const float*)d_in[2];
    const float* offset_b = (const float*)d_in[3];
    const float* deform_w = (const float*)d_in[4];
    float* out  = (float*)d_out;

    float* offs = (float*)d_ws;               // 9.44 MB
    float* wt2  = offs + OFFS_ELEMS;          // 46 KB
    float* wt   = wt2 + WT2_ELEMS;            // 9.2 KB

    hipLaunchKernelGGL(transpose_w_kernel, dim3(8), dim3(256), 0, stream,
                       offset_w, deform_w, wt2, wt);
    hipLaunchKernelGGL(init_offs_kernel, dim3((OFFS_ELEMS / 4 + 255) / 256), dim3(256),
                       0, stream, offset_b, offs);
    hipLaunchKernelGGL(offset_conv_kernel, dim3(Hn / 4, Bn, CSPLIT), dim3(256),
                       0, stream, x, wt2, offs);
    hipLaunchKernelGGL(deform_kernel, dim3(Hn / 4, Bn * NG), dim3(256),
                       0, stream, skip, offs, wt, out);
}